// Round 6
// baseline (584.293 us; speedup 1.0000x reference)
//
#include <hip/hip_runtime.h>
#include <cstdint>
#include <cstddef>

#define H 64
#define C 7
#define F 20
#define BSH 9
#define BSZ 512
#define CH 8192

typedef unsigned short u16;
typedef __attribute__((ext_vector_type(8))) short bf16x8;
typedef __attribute__((ext_vector_type(4))) float f32x4;

static __device__ __forceinline__ int imax(int a, int b) { return a > b ? a : b; }
static __device__ __forceinline__ int imin(int a, int b) { return a < b ? a : b; }

static __device__ __forceinline__ float bf2f(u16 v) {
  union { unsigned u; float f; } x; x.u = ((unsigned)v) << 16; return x.f;
}
static __device__ __forceinline__ u16 f2bf(float f) {  // round-nearest-even
  union { float f; unsigned u; } x; x.f = f;
  unsigned r = x.u + 0x7fffu + ((x.u >> 16) & 1u);
  return (u16)(r >> 16);
}
static __device__ __forceinline__ int pack2bf(float a, float b) {
  return (int)f2bf(a) | ((int)f2bf(b) << 16);
}
static __device__ __forceinline__ float lo16f(unsigned v) {
  union { unsigned u; float f; } x; x.u = v << 16; return x.f;
}
static __device__ __forceinline__ float hi16f(unsigned v) {
  union { unsigned u; float f; } x; x.u = v & 0xffff0000u; return x.f;
}

// ---------- phase 1: coarse bucket histogram ----------
__global__ __launch_bounds__(256) void k_bhist(const int* __restrict__ esrc,
                                               const int* __restrict__ edst, int E,
                                               int* __restrict__ gcnt_u, int* __restrict__ gcnt_m,
                                               int nbu, int nbm) {
  extern __shared__ int sh[];
  int* hu = sh;
  int* hm = sh + nbu;
  for (int i = threadIdx.x; i < nbu + nbm; i += 256) sh[i] = 0;
  __syncthreads();
  int stride = gridDim.x * 256;
  for (int i = blockIdx.x * 256 + threadIdx.x; i < E; i += stride) {
    atomicAdd(&hu[esrc[i] >> BSH], 1);
    atomicAdd(&hm[edst[i] >> BSH], 1);
  }
  __syncthreads();
  for (int i = threadIdx.x; i < nbu; i += 256) if (hu[i]) atomicAdd(&gcnt_u[i], hu[i]);
  for (int i = threadIdx.x; i < nbm; i += 256) if (hm[i]) atomicAdd(&gcnt_m[i], hm[i]);
}

// ---------- phase 2: scan bucket counts ----------
__global__ __launch_bounds__(256) void k_bscan(const int* __restrict__ gcnt_u,
                                               const int* __restrict__ gcnt_m,
                                               int nbu, int nbm, int E,
                                               int* __restrict__ boff_u, int* __restrict__ boff_m,
                                               int* __restrict__ gcur_u, int* __restrict__ gcur_m) {
  __shared__ int s[1024];
  for (int i = threadIdx.x; i < nbu; i += 256) s[i] = gcnt_u[i];
  for (int i = threadIdx.x; i < nbm; i += 256) s[512 + i] = gcnt_m[i];
  __syncthreads();
  if (threadIdx.x == 0) {
    int r = 0;
    for (int i = 0; i < nbu; ++i) { int v = s[i]; s[i] = r; r += v; }
  }
  if (threadIdx.x == 1) {
    int r = 0;
    for (int i = 0; i < nbm; ++i) { int v = s[512 + i]; s[512 + i] = r; r += v; }
  }
  __syncthreads();
  for (int i = threadIdx.x; i < nbu; i += 256) { boff_u[i] = s[i]; gcur_u[i] = s[i]; }
  for (int i = threadIdx.x; i < nbm; i += 256) { boff_m[i] = s[512 + i]; gcur_m[i] = s[512 + i]; }
  if (threadIdx.x == 0) { boff_u[nbu] = E; boff_m[nbm] = E; }
}

// ---------- phase 3: binning scatter into coarse buckets ----------
__global__ __launch_bounds__(256) void k_bscat(const int* __restrict__ esrc,
                                               const int* __restrict__ edst, int E,
                                               int* __restrict__ gcur_u, int* __restrict__ gcur_m,
                                               unsigned int* __restrict__ pk_u,
                                               unsigned int* __restrict__ pk_m,
                                               int nbu, int nbm, int nchunks) {
  extern __shared__ int sh2[];
  int dir = (blockIdx.x >= (unsigned)nchunks) ? 1 : 0;
  int chunk = dir ? (blockIdx.x - nchunks) : blockIdx.x;
  const int* key = dir ? edst : esrc;
  const int* pay = dir ? esrc : edst;
  int* gcur = dir ? gcur_m : gcur_u;
  unsigned int* pk = dir ? pk_m : pk_u;
  int nb = dir ? nbm : nbu;
  int* cnt = sh2;
  int* base = sh2 + nb;
  int beg = chunk * CH;
  int end = imin(beg + CH, E);
  for (int i = threadIdx.x; i < nb; i += 256) cnt[i] = 0;
  __syncthreads();
  for (int i = beg + threadIdx.x; i < end; i += 256) atomicAdd(&cnt[key[i] >> BSH], 1);
  __syncthreads();
  for (int i = threadIdx.x; i < nb; i += 256) {
    int c = cnt[i];
    base[i] = c ? atomicAdd(&gcur[i], c) : 0;
    cnt[i] = 0;
  }
  __syncthreads();
  for (int i = beg + threadIdx.x; i < end; i += 256) {
    int k = key[i];
    int b = k >> BSH;
    int r = atomicAdd(&cnt[b], 1);
    pk[base[b] + r] = ((unsigned)(k & (BSZ - 1)) << 18) | (unsigned)pay[i];
  }
}

// ---------- phase 4: per-bucket CSR build ----------
__global__ __launch_bounds__(512) void k_bbuild(const unsigned int* __restrict__ pk_u,
                                                const unsigned int* __restrict__ pk_m,
                                                const int* __restrict__ boff_u,
                                                const int* __restrict__ boff_m,
                                                int nbu, int nbm, int U_, int M_, int E,
                                                int* __restrict__ csr_u, int* __restrict__ csr_m,
                                                int* __restrict__ off_u, int* __restrict__ off_m) {
  __shared__ int hist[BSZ];
  __shared__ int cur[BSZ];
  int dir = (blockIdx.x >= (unsigned)nbu) ? 1 : 0;
  int b = dir ? (blockIdx.x - nbu) : blockIdx.x;
  const unsigned int* pk = dir ? pk_m : pk_u;
  const int* boff = dir ? boff_m : boff_u;
  int N = dir ? M_ : U_;
  int nb = dir ? nbm : nbu;
  int* csr = dir ? csr_m : csr_u;
  int* off = dir ? off_m : off_u;
  int beg = boff[b], end = boff[b + 1];
  int t = threadIdx.x;
  hist[t] = 0;
  __syncthreads();
  for (int i = beg + t; i < end; i += 512) atomicAdd(&hist[pk[i] >> 18], 1);
  __syncthreads();
  int v0 = hist[t];
  for (int o = 1; o < 512; o <<= 1) {
    int x = (t >= o) ? hist[t - o] : 0;
    __syncthreads();
    hist[t] += x;
    __syncthreads();
  }
  int excl = hist[t] - v0;
  cur[t] = excl;
  int node = (b << BSH) + t;
  if (node < N) off[node] = beg + excl;
  if (t == 0 && b == nb - 1) off[N] = E;
  __syncthreads();
  for (int i = beg + t; i < end; i += 512) {
    unsigned int p = pk[i];
    int n = (int)(p >> 18);
    int r = atomicAdd(&cur[n], 1);
    csr[beg + r] = (int)(p & 0x3FFFFu);
  }
}

// ---------- merged prep: movie projection + user cvt + combined classifier weights ----------
__global__ __launch_bounds__(256) void k_prep(
    const float* __restrict__ movie_x, const float* __restrict__ w_movie,
    const float* __restrict__ b_movie, const float* __restrict__ movie_emb,
    const int* __restrict__ mnid,
    const float* __restrict__ user_emb, const int* __restrict__ unid,
    const float* __restrict__ l2u_Wl, const float* __restrict__ l2u_Wr,
    const float* __restrict__ l2u_bl,
    const float* __restrict__ l2m_Wl, const float* __restrict__ l2m_Wr,
    const float* __restrict__ l2m_bl,
    const float* __restrict__ clsW,
    u16* __restrict__ xm_bf, u16* __restrict__ xu_bf, float* __restrict__ cw,
    int M_, int U_, int gProj, int gCvt) {
  __shared__ float ws_[F * H];
  int b = blockIdx.x;
  if (b < gProj) {
    for (int i = threadIdx.x; i < F * H; i += 256) ws_[i] = w_movie[i];
    __syncthreads();
    int t = b * 256 + threadIdx.x;
    int m = t >> 6;
    int h = t & 63;
    if (m >= M_) return;
    float acc = b_movie[h] + movie_emb[(size_t)mnid[m] * H + h];
    const float* xr = movie_x + (size_t)m * F;
    #pragma unroll
    for (int f = 0; f < F; ++f) acc += xr[f] * ws_[f * H + h];
    xm_bf[(size_t)m * H + h] = f2bf(acc);
  } else if (b < gProj + gCvt) {
    int t = (b - gProj) * 256 + threadIdx.x;
    if (t >= U_ * 16) return;
    int i = t >> 4;
    int g = t & 15;
    const float4 v = *(const float4*)(user_emb + (size_t)unid[i] * H + g * 4);
    ushort4 o;
    o.x = f2bf(v.x); o.y = f2bf(v.y); o.z = f2bf(v.z); o.w = f2bf(v.w);
    *(ushort4*)(xu_bf + (size_t)i * H + g * 4) = o;
  } else {
    int t = (b - gProj - gCvt) * 256 + threadIdx.x;
    if (t < 448) {
      int k = t / C, c = t % C;
      float s = 0.f;
      for (int j = 0; j < H; ++j) s += l2u_Wl[k * H + j] * clsW[j * C + c];
      cw[t] = s;
    } else if (t < 896) {
      int u = t - 448; int k = u / C, c = u % C;
      float s = 0.f;
      for (int j = 0; j < H; ++j) s += l2u_Wr[k * H + j] * clsW[j * C + c];
      cw[t] = s;
    } else if (t < 1344) {
      int u = t - 896; int k = u / C, c = u % C;
      float s = 0.f;
      for (int j = 0; j < H; ++j) s += l2m_Wl[k * H + j] * clsW[(H + j) * C + c];
      cw[t] = s;
    } else if (t < 1792) {
      int u = t - 1344; int k = u / C, c = u % C;
      float s = 0.f;
      for (int j = 0; j < H; ++j) s += l2m_Wr[k * H + j] * clsW[(H + j) * C + c];
      cw[t] = s;
    } else if (t < 1799) {
      int c = t - 1792;
      float s = 0.f;
      for (int j = 0; j < H; ++j) s += l2u_bl[j] * clsW[j * C + c];
      cw[t] = s;
    } else if (t < 1806) {
      int c = t - 1799;
      float s = 0.f;
      for (int j = 0; j < H; ++j) s += l2m_bl[j] * clsW[(H + j) * C + c];
      cw[t] = s;
    }
  }
}

// ---------- fused SAGE layer-1: register-direct gather in MFMA A-layout ----------
// 256 threads = 4 waves, 16 nodes/wave, 64 nodes/block. Lane (q4=lane>>4, r16=lane&15)
// owns node r16's feature cols [kt*32 + q4*8, +8) (kt=0,1): per neighbor it loads two
// dwordx4 (4 lanes cover the 128B row) and accumulates 16 fp32 cols -> exactly the
// MFMA A-fragment. No LDS for agg, no shfl distribution. hi+lo bf16 split keeps the
// aggregate fp32-exact through the MFMA.
__global__ __launch_bounds__(256, 6) void k_sage_mfma(
    const u16* __restrict__ xu, const u16* __restrict__ xm,
    const int* __restrict__ csr_u, const int* __restrict__ off_u,
    const int* __restrict__ csr_m, const int* __restrict__ off_m,
    const float* __restrict__ WlU, const float* __restrict__ blU, const float* __restrict__ WrU,
    const float* __restrict__ WlM, const float* __restrict__ blM, const float* __restrict__ WrM,
    const float* __restrict__ CWml, const float* __restrict__ CWur,   // user-side Z parts
    const float* __restrict__ CWul, const float* __restrict__ CWmr,   // movie-side Z parts
    u16* __restrict__ Zu, u16* __restrict__ Zm,
    int U_, int M_, int E_, int gU) {
  __shared__ int sWl[64 * 36];
  __shared__ int sWr[64 * 36];
  __shared__ float sCl[448];
  __shared__ float sCr[448];
  __shared__ float sBl[64];

  int movie = (blockIdx.x >= (unsigned)gU) ? 1 : 0;
  int bside = movie ? (blockIdx.x - gU) : blockIdx.x;
  const u16* srcT = movie ? xu : xm;
  const u16* rootT = movie ? xm : xu;
  const int* csr = movie ? csr_m : csr_u;
  const int* off = movie ? off_m : off_u;
  const float* Wl = movie ? WlM : WlU;
  const float* Wr = movie ? WrM : WrU;
  const float* bl = movie ? blM : blU;
  const float* CWl = movie ? CWul : CWml;
  const float* CWr = movie ? CWmr : CWur;
  u16* Z = movie ? Zm : Zu;
  int N = movie ? M_ : U_;

  int tid = threadIdx.x;
  // stage weights: W^T as bf16 pairs (row j = output col, 32 dwords + 4 pad)
  for (int idx = tid; idx < 2048; idx += 256) {
    int j = idx & 63, kk = idx >> 6;
    sWl[j * 36 + kk] = pack2bf(Wl[(2 * kk) * H + j], Wl[(2 * kk + 1) * H + j]);
    sWr[j * 36 + kk] = pack2bf(Wr[(2 * kk) * H + j], Wr[(2 * kk + 1) * H + j]);
  }
  for (int idx = tid; idx < 448; idx += 256) { sCl[idx] = CWl[idx]; sCr[idx] = CWr[idx]; }
  if (tid < 64) sBl[tid] = bl[tid];
  __syncthreads();

  int lane = tid & 63;
  int wid = tid >> 6;
  int r16 = lane & 15;
  int q4 = lane >> 4;
  int node0 = bside * 64 + wid * 16;
  int n = node0 + r16;
  int nc = imin(n, N - 1);
  int jb = off[nc];
  int d = off[nc + 1] - jb;
  if (n >= N) d = 0;
  int dm1 = imax(d - 1, 0);
  int Em1 = E_ - 1;

  int dmax = d;
  dmax = imax(dmax, __shfl_xor(dmax, 1));
  dmax = imax(dmax, __shfl_xor(dmax, 2));
  dmax = imax(dmax, __shfl_xor(dmax, 4));
  dmax = imax(dmax, __shfl_xor(dmax, 8));

  const u16* sb = srcT + q4 * 8;
  float a0c[8] = {0.f, 0.f, 0.f, 0.f, 0.f, 0.f, 0.f, 0.f};   // cols q4*8..+8 (kt=0)
  float a1c[8] = {0.f, 0.f, 0.f, 0.f, 0.f, 0.f, 0.f, 0.f};   // cols 32+q4*8..+8 (kt=1)

  for (int t = 0; t < dmax; t += 2) {
    int c0 = imin(jb + imin(t, dm1), Em1);
    int c1 = imin(jb + imin(t + 1, dm1), Em1);
    int e0 = csr[c0];
    int e1 = csr[c1];
    const u16* p0 = sb + (size_t)(unsigned)e0 * H;
    const u16* p1 = sb + (size_t)(unsigned)e1 * H;
    uint4 v00 = *(const uint4*)p0;
    uint4 v01 = *(const uint4*)(p0 + 32);
    uint4 v10 = *(const uint4*)p1;
    uint4 v11 = *(const uint4*)(p1 + 32);
    float m0 = (t < d) ? 1.0f : 0.0f;
    float m1 = (t + 1 < d) ? 1.0f : 0.0f;
    a0c[0] = fmaf(lo16f(v00.x), m0, a0c[0]); a0c[1] = fmaf(hi16f(v00.x), m0, a0c[1]);
    a0c[2] = fmaf(lo16f(v00.y), m0, a0c[2]); a0c[3] = fmaf(hi16f(v00.y), m0, a0c[3]);
    a0c[4] = fmaf(lo16f(v00.z), m0, a0c[4]); a0c[5] = fmaf(hi16f(v00.z), m0, a0c[5]);
    a0c[6] = fmaf(lo16f(v00.w), m0, a0c[6]); a0c[7] = fmaf(hi16f(v00.w), m0, a0c[7]);
    a1c[0] = fmaf(lo16f(v01.x), m0, a1c[0]); a1c[1] = fmaf(hi16f(v01.x), m0, a1c[1]);
    a1c[2] = fmaf(lo16f(v01.y), m0, a1c[2]); a1c[3] = fmaf(hi16f(v01.y), m0, a1c[3]);
    a1c[4] = fmaf(lo16f(v01.z), m0, a1c[4]); a1c[5] = fmaf(hi16f(v01.z), m0, a1c[5]);
    a1c[6] = fmaf(lo16f(v01.w), m0, a1c[6]); a1c[7] = fmaf(hi16f(v01.w), m0, a1c[7]);
    a0c[0] = fmaf(lo16f(v10.x), m1, a0c[0]); a0c[1] = fmaf(hi16f(v10.x), m1, a0c[1]);
    a0c[2] = fmaf(lo16f(v10.y), m1, a0c[2]); a0c[3] = fmaf(hi16f(v10.y), m1, a0c[3]);
    a0c[4] = fmaf(lo16f(v10.z), m1, a0c[4]); a0c[5] = fmaf(hi16f(v10.z), m1, a0c[5]);
    a0c[6] = fmaf(lo16f(v10.w), m1, a0c[6]); a0c[7] = fmaf(hi16f(v10.w), m1, a0c[7]);
    a1c[0] = fmaf(lo16f(v11.x), m1, a1c[0]); a1c[1] = fmaf(hi16f(v11.x), m1, a1c[1]);
    a1c[2] = fmaf(lo16f(v11.y), m1, a1c[2]); a1c[3] = fmaf(hi16f(v11.y), m1, a1c[3]);
    a1c[4] = fmaf(lo16f(v11.z), m1, a1c[4]); a1c[5] = fmaf(hi16f(v11.z), m1, a1c[5]);
    a1c[6] = fmaf(lo16f(v11.w), m1, a1c[6]); a1c[7] = fmaf(hi16f(v11.w), m1, a1c[7]);
  }

  // finalize: mean, hi/lo bf16 split -> A fragments in registers
  union FU { int4 i; bf16x8 b; };
  FU ahi[2], alo[2], art[2];
  float inv = 1.0f / (float)imax(d, 1);
  {
    int h4[4], l4[4];
    #pragma unroll
    for (int pp = 0; pp < 4; ++pp) {
      float s0 = a0c[2 * pp] * inv, s1 = a0c[2 * pp + 1] * inv;
      u16 b0 = f2bf(s0), b1 = f2bf(s1);
      h4[pp] = (int)b0 | ((int)b1 << 16);
      l4[pp] = pack2bf(s0 - bf2f(b0), s1 - bf2f(b1));
    }
    ahi[0].i = make_int4(h4[0], h4[1], h4[2], h4[3]);
    alo[0].i = make_int4(l4[0], l4[1], l4[2], l4[3]);
    #pragma unroll
    for (int pp = 0; pp < 4; ++pp) {
      float s0 = a1c[2 * pp] * inv, s1 = a1c[2 * pp + 1] * inv;
      u16 b0 = f2bf(s0), b1 = f2bf(s1);
      h4[pp] = (int)b0 | ((int)b1 << 16);
      l4[pp] = pack2bf(s0 - bf2f(b0), s1 - bf2f(b1));
    }
    ahi[1].i = make_int4(h4[0], h4[1], h4[2], h4[3]);
    alo[1].i = make_int4(l4[0], l4[1], l4[2], l4[3]);
  }
  #pragma unroll
  for (int kt = 0; kt < 2; ++kt)
    art[kt].i = *(const int4*)(rootT + (size_t)nc * H + kt * 32 + q4 * 8);

  // ---- MFMA transform ----
  float val[4][4];
  #pragma unroll
  for (int t = 0; t < 4; ++t) {
    f32x4 cacc = {0.f, 0.f, 0.f, 0.f};
    #pragma unroll
    for (int kt = 0; kt < 2; ++kt) {
      FU bwl, bwr;
      bwl.i = *(const int4*)&sWl[(t * 16 + r16) * 36 + kt * 16 + q4 * 4];
      bwr.i = *(const int4*)&sWr[(t * 16 + r16) * 36 + kt * 16 + q4 * 4];
      cacc = __builtin_amdgcn_mfma_f32_16x16x32_bf16(ahi[kt].b, bwl.b, cacc, 0, 0, 0);
      cacc = __builtin_amdgcn_mfma_f32_16x16x32_bf16(alo[kt].b, bwl.b, cacc, 0, 0, 0);
      cacc = __builtin_amdgcn_mfma_f32_16x16x32_bf16(art[kt].b, bwr.b, cacc, 0, 0, 0);
    }
    float bj = sBl[t * 16 + r16];
    #pragma unroll
    for (int r = 0; r < 4; ++r) val[t][r] = fmaxf(cacc[r] + bj, 0.f);
  }

  // ---- classifier projection: Z[node][c] (c<7: @CWl), Z[node][8+c] (@CWr) ----
  float zacc[4] = {0.f, 0.f, 0.f, 0.f};
  #pragma unroll
  for (int c = 0; c < C; ++c) {
    float tl[4], tr[4];
    #pragma unroll
    for (int r = 0; r < 4; ++r) {
      tl[r] = val[0][r] * sCl[(r16) * C + c] + val[1][r] * sCl[(16 + r16) * C + c] +
              val[2][r] * sCl[(32 + r16) * C + c] + val[3][r] * sCl[(48 + r16) * C + c];
      tr[r] = val[0][r] * sCr[(r16) * C + c] + val[1][r] * sCr[(16 + r16) * C + c] +
              val[2][r] * sCr[(32 + r16) * C + c] + val[3][r] * sCr[(48 + r16) * C + c];
    }
    #pragma unroll
    for (int o = 1; o < 16; o <<= 1) {
      #pragma unroll
      for (int r = 0; r < 4; ++r) {
        tl[r] += __shfl_xor(tl[r], o);
        tr[r] += __shfl_xor(tr[r], o);
      }
    }
    #pragma unroll
    for (int r = 0; r < 4; ++r) {
      zacc[r] = (r16 == c) ? zacc[r] + tl[r] : zacc[r];
      zacc[r] = (r16 == 8 + c) ? zacc[r] + tr[r] : zacc[r];
    }
  }
  #pragma unroll
  for (int r = 0; r < 4; ++r) {
    int node = node0 + q4 * 4 + r;
    if (node < N) Z[(size_t)node * 16 + r16] = f2bf(zacc[r]);
  }
}

// ---------- merged layer-2 aggregation in projected bf16 space ----------
__global__ __launch_bounds__(256) void k_agg7m(
    const u16* __restrict__ Zu, const u16* __restrict__ Zm,
    const int* __restrict__ csr_u, const int* __restrict__ off_u,
    const int* __restrict__ csr_m, const int* __restrict__ off_m,
    const float* __restrict__ cbu, const float* __restrict__ cbm,
    float* __restrict__ Pu, float* __restrict__ Pm,
    int U_, int M_, int gU) {
  int movie = (blockIdx.x >= (unsigned)gU) ? 1 : 0;
  int bside = movie ? (blockIdx.x - gU) : blockIdx.x;
  const u16* Zsrc = movie ? Zu : Zm;
  const u16* Zroot = movie ? Zm : Zu;
  const int* csr = movie ? csr_m : csr_u;
  const int* off = movie ? off_m : off_u;
  const float* cb = movie ? cbm : cbu;
  float* P = movie ? Pm : Pu;
  int N = movie ? M_ : U_;

  int n = bside * 256 + threadIdx.x;
  if (n >= N) return;
  int beg = off[n], end = off[n + 1];
  float acc[8] = {0.f, 0.f, 0.f, 0.f, 0.f, 0.f, 0.f, 0.f};
  int j = beg;
  for (; j + 2 <= end; j += 2) {
    int a0 = csr[j], a1 = csr[j + 1];
    uint4 z0 = *(const uint4*)(Zsrc + (size_t)a0 * 16);
    uint4 z1 = *(const uint4*)(Zsrc + (size_t)a1 * 16);
    acc[0] += lo16f(z0.x); acc[1] += hi16f(z0.x);
    acc[2] += lo16f(z0.y); acc[3] += hi16f(z0.y);
    acc[4] += lo16f(z0.z); acc[5] += hi16f(z0.z);
    acc[6] += lo16f(z0.w); acc[7] += hi16f(z0.w);
    acc[0] += lo16f(z1.x); acc[1] += hi16f(z1.x);
    acc[2] += lo16f(z1.y); acc[3] += hi16f(z1.y);
    acc[4] += lo16f(z1.z); acc[5] += hi16f(z1.z);
    acc[6] += lo16f(z1.w); acc[7] += hi16f(z1.w);
  }
  if (j < end) {
    int a0 = csr[j];
    uint4 z0 = *(const uint4*)(Zsrc + (size_t)a0 * 16);
    acc[0] += lo16f(z0.x); acc[1] += hi16f(z0.x);
    acc[2] += lo16f(z0.y); acc[3] += hi16f(z0.y);
    acc[4] += lo16f(z0.z); acc[5] += hi16f(z0.z);
    acc[6] += lo16f(z0.w); acc[7] += hi16f(z0.w);
  }
  float inv = 1.f / (float)imax(end - beg, 1);
  uint4 zr = *(const uint4*)(Zroot + (size_t)n * 16 + 8);
  float4 o0, o1;
  o0.x = acc[0] * inv + lo16f(zr.x) + cb[0];
  o0.y = acc[1] * inv + hi16f(zr.x) + cb[1];
  o0.z = acc[2] * inv + lo16f(zr.y) + cb[2];
  o0.w = acc[3] * inv + hi16f(zr.y) + cb[3];
  o1.x = acc[4] * inv + lo16f(zr.z) + cb[4];
  o1.y = acc[5] * inv + hi16f(zr.z) + cb[5];
  o1.z = acc[6] * inv + lo16f(zr.w) + cb[6];
  o1.w = 0.f;
  float4* po = (float4*)(P + (size_t)n * 8);
  po[0] = o0;
  po[1] = o1;
}

// ---------- final edge classifier ----------
__global__ void k_final(const int* __restrict__ els, const int* __restrict__ eld,
                        const float* __restrict__ Pu, const float* __restrict__ Pm,
                        const float* __restrict__ clsb, float* __restrict__ out, int total) {
  int t = blockIdx.x * 256 + threadIdx.x;
  if (t >= total) return;
  int e = t / C, c = t - e * C;
  out[t] = Pu[(size_t)els[e] * 8 + c] + Pm[(size_t)eld[e] * 8 + c] + clsb[c];
}

extern "C" void kernel_launch(void* const* d_in, const int* in_sizes, int n_in,
                              void* d_out, int out_size, void* d_ws, size_t ws_size,
                              hipStream_t stream) {
  (void)n_in; (void)out_size; (void)ws_size;
  const int*   unid      = (const int*)d_in[0];
  const int*   mnid      = (const int*)d_in[1];
  const float* movie_x   = (const float*)d_in[2];
  const int*   e_src     = (const int*)d_in[3];
  const int*   e_dst     = (const int*)d_in[4];
  const int*   el_src    = (const int*)d_in[5];
  const int*   el_dst    = (const int*)d_in[6];
  const float* user_emb  = (const float*)d_in[7];
  const float* movie_emb = (const float*)d_in[8];
  const float* w_movie   = (const float*)d_in[9];
  const float* b_movie   = (const float*)d_in[10];
  const float* l1r_Wl    = (const float*)d_in[11];
  const float* l1r_bl    = (const float*)d_in[12];
  const float* l1r_Wr    = (const float*)d_in[13];
  const float* l1v_Wl    = (const float*)d_in[14];
  const float* l1v_bl    = (const float*)d_in[15];
  const float* l1v_Wr    = (const float*)d_in[16];
  const float* l2r_Wl    = (const float*)d_in[17];
  const float* l2r_bl    = (const float*)d_in[18];
  const float* l2r_Wr    = (const float*)d_in[19];
  const float* l2v_Wl    = (const float*)d_in[20];
  const float* l2v_bl    = (const float*)d_in[21];
  const float* l2v_Wr    = (const float*)d_in[22];
  const float* cls_W     = (const float*)d_in[23];
  const float* cls_b     = (const float*)d_in[24];

  int U  = in_sizes[0];
  int M  = in_sizes[1];
  int E  = in_sizes[3];
  int EL = in_sizes[5];

  int nbu = (U + BSZ - 1) / BSZ;
  int nbm = (M + BSZ - 1) / BSZ;
  int nchunks = (E + CH - 1) / CH;

  char* p = (char*)d_ws;
  auto alloc = [&](size_t nbytes) { char* r = p; p += (nbytes + 255) & ~(size_t)255; return r; };

  u16*   xm_bf  = (u16*)alloc((size_t)M * H * 2);
  u16*   xu_bf  = (u16*)alloc((size_t)U * H * 2);
  u16*   Zu     = (u16*)alloc((size_t)U * 16 * 2);
  u16*   Zm     = (u16*)alloc((size_t)M * 16 * 2);
  float* Pu     = (float*)alloc((size_t)U * 8 * 4);
  float* Pm     = (float*)alloc((size_t)M * 8 * 4);
  int*   csr_u  = (int*)alloc((size_t)E * 4);
  int*   csr_m  = (int*)alloc((size_t)E * 4);
  int*   off_u  = (int*)alloc((size_t)(U + 1) * 4);
  int*   off_m  = (int*)alloc((size_t)(M + 1) * 4);
  unsigned int* pk_u = (unsigned int*)alloc((size_t)E * 4);
  unsigned int* pk_m = (unsigned int*)alloc((size_t)E * 4);
  int*   gcnt   = (int*)alloc((size_t)(nbu + nbm) * 4);
  int*   gcnt_u = gcnt;
  int*   gcnt_m = gcnt + nbu;
  int*   boff_u = (int*)alloc((size_t)(nbu + 1) * 4);
  int*   boff_m = (int*)alloc((size_t)(nbm + 1) * 4);
  int*   gcur_u = (int*)alloc((size_t)nbu * 4);
  int*   gcur_m = (int*)alloc((size_t)nbm * 4);
  float* cw     = (float*)alloc(1806 * 4);
  float* CWul = cw, *CWur = cw + 448, *CWml = cw + 896, *CWmr = cw + 1344;
  float* cbu  = cw + 1792, *cbm = cw + 1799;

  hipMemsetAsync(gcnt, 0, (size_t)(nbu + nbm) * 4, stream);

  // ---- CSR build ----
  k_bhist<<<256, 256, (size_t)(nbu + nbm) * 4, stream>>>(e_src, e_dst, E, gcnt_u, gcnt_m, nbu, nbm);
  k_bscan<<<1, 256, 0, stream>>>(gcnt_u, gcnt_m, nbu, nbm, E, boff_u, boff_m, gcur_u, gcur_m);
  k_bscat<<<2 * nchunks, 256, (size_t)(2 * nbu) * 4, stream>>>(e_src, e_dst, E, gcur_u, gcur_m,
                                                               pk_u, pk_m, nbu, nbm, nchunks);
  k_bbuild<<<nbu + nbm, 512, 0, stream>>>(pk_u, pk_m, boff_u, boff_m, nbu, nbm, U, M, E,
                                          csr_u, csr_m, off_u, off_m);

  // ---- merged prep (bf16 tables + combined classifier weights) ----
  int gProj = (M * H + 255) / 256;
  int gCvt  = (U * 16 + 255) / 256;
  k_prep<<<gProj + gCvt + 8, 256, 0, stream>>>(
      movie_x, w_movie, b_movie, movie_emb, mnid, user_emb, unid,
      l2v_Wl, l2v_Wr, l2v_bl, l2r_Wl, l2r_Wr, l2r_bl, cls_W,
      xm_bf, xu_bf, cw, M, U, gProj, gCvt);

  // ---- merged layer-1 (MFMA, register-direct gather) fused with classifier projection ----
  int gU_s = (U + 63) / 64;
  int gM_s = (M + 63) / 64;
  k_sage_mfma<<<gU_s + gM_s, 256, 0, stream>>>(
      xu_bf, xm_bf, csr_u, off_u, csr_m, off_m,
      l1v_Wl, l1v_bl, l1v_Wr,
      l1r_Wl, l1r_bl, l1r_Wr,
      CWml, CWur, CWul, CWmr,
      Zu, Zm, U, M, E, gU_s);

  // ---- merged layer-2 aggregation ----
  int gU_a = (U + 255) / 256;
  int gM_a = (M + 255) / 256;
  k_agg7m<<<gU_a + gM_a, 256, 0, stream>>>(Zu, Zm, csr_u, off_u, csr_m, off_m,
                                           cbu, cbm, Pu, Pm, U, M, gU_a);

  // ---- final ----
  int total = EL * C;
  k_final<<<(total + 255) / 256, 256, 0, stream>>>(el_src, el_dst, Pu, Pm, cls_b, (float*)d_out, total);
}